// Round 15
// baseline (180.100 us; speedup 1.0000x reference)
//
#include <hip/hip_runtime.h>
#include <hip/hip_bf16.h>

// MultiHeadBatchedMixers, group-sorted two-kernel structure (no atomics):
//   prepack+sort: w1t,w2t,x,w1c,w2c -> bf16 ws (biases stay f32; L2-hot, no cvt);
//                 block 0 builds order[768] (by (e,h)) / order2[384] (by (e0,h))
//   Kernel A (grid 1536x256, XCD-chunked, group-ordered): H = GELU(W1c @ X @ W1t^T + B1)
//       e-half split: 32-e pipelines with non-overlapping acc lifetimes -> ~2x occupancy
//   Kernel B (grid 768x256, XCD-chunked, group-ordered): 4 waves = 2 k x 2 wq,
//       wave owns 64c x 64n (intensity 2); LDS combine; plain f32 stores
// bf16 MFMA 16x16x32, f32 accumulate.
// NOTE (R8/R10): VGPR+AGPR share one file on gfx950; never min-waves-bound the
// MFMA kernels (reg cap -> accumulator spill -> WRITE blowup).
// NOTE (R12/R13/R14): cost tracks TOTAL load instructions & MFMA/load intensity;
// intensity-2 64x64 wave tiles beat high-occupancy thin tiles. R14->R15: the next
// cap was accumulator register footprint (acc1+acc2 = 128 regs live) -> e-half split.

namespace {
constexpr int NHEAD = 12, NTOK = 256, HDIM = 64, HIDD = 512, NBATCH = 32, TOPK = 2;
constexpr int NCHAIN = NBATCH * NHEAD * TOPK;  // 768
constexpr int NBH = NBATCH * NHEAD;            // 384
constexpr int NGROUP = 8 * NHEAD;              // 96

// Kernel A LDS: per-wave T1^T [32 e][64 d] bf16, pitch +16B (reused per e-half)
constexpr int P_T1 = HDIM * 2 + 16;   // 144
constexpr int T1_W = 32 * P_T1;       // 4608
constexpr int SMA_TOTAL = 4 * T1_W;   // 18432
// Kernel B LDS: per-wave T3^T [64 n][64 c] (4 waves); combine aliases [0,32768)
constexpr int P_T3 = HDIM * 2 + 16;   // 144
constexpr int T3_W = 64 * P_T3;       // 9216
constexpr int SMB_TOTAL = 4 * T3_W;   // 36864

// ws layout: [H][w1t][w2t][x][b1(unused)][b2(unused)][w1c][w2c] bf16, then orders
constexpr size_t SZ_H    = (size_t)NCHAIN * HDIM * HIDD;          // 25,165,824
constexpr size_t OFF_H   = 0;
constexpr size_t OFF_W1T = OFF_H + SZ_H;
constexpr size_t SZ_W1T  = (size_t)8 * NHEAD * HIDD * NTOK;       // 12,582,912
constexpr size_t OFF_W2T = OFF_W1T + SZ_W1T;
constexpr size_t SZ_W2T  = (size_t)8 * NHEAD * NTOK * HIDD;
constexpr size_t OFF_X   = OFF_W2T + SZ_W2T;
constexpr size_t SZ_X    = (size_t)NBATCH * NHEAD * HDIM * NTOK;  // 6,291,456
constexpr size_t OFF_B1  = OFF_X + SZ_X;
constexpr size_t SZ_B1   = (size_t)8 * NHEAD * HDIM * HIDD;
constexpr size_t OFF_B2  = OFF_B1 + SZ_B1;
constexpr size_t SZ_B2   = (size_t)8 * NHEAD * HDIM * NTOK;
constexpr size_t OFF_W1C = OFF_B2 + SZ_B2;
constexpr size_t SZ_W1C  = (size_t)8 * NHEAD * HDIM * HDIM;       // 393,216
constexpr size_t OFF_W2C = OFF_W1C + SZ_W1C;
constexpr size_t SZ_W2C  = (size_t)8 * NHEAD * HDIM * HDIM;
constexpr size_t TOTEL   = OFF_W2C + SZ_W2C;                      // shorts
constexpr size_t NEED    = TOTEL * 2 + (NCHAIN + NBH) * 4;
}

typedef float f32x4 __attribute__((ext_vector_type(4)));
typedef short bf16x8 __attribute__((ext_vector_type(8)));
typedef short bf16x4 __attribute__((ext_vector_type(4)));

#define MFMA16(a, b, c) __builtin_amdgcn_mfma_f32_16x16x32_bf16((a), (b), (c), 0, 0, 0)

__device__ __forceinline__ short f2bf(float f) {
  union { float f; unsigned u; } v; v.f = f;
  unsigned r = v.u + 0x7fffu + ((v.u >> 16) & 1u);
  return (short)(r >> 16);
}

__device__ __forceinline__ bf16x8 ld_gfrag(const float* p) {
  float4 a = *(const float4*)p;
  float4 b = *(const float4*)(p + 4);
  bf16x8 r;
  r[0] = f2bf(a.x); r[1] = f2bf(a.y); r[2] = f2bf(a.z); r[3] = f2bf(a.w);
  r[4] = f2bf(b.x); r[5] = f2bf(b.y); r[6] = f2bf(b.z); r[7] = f2bf(b.w);
  return r;
}

// gelu(x) = x / (1 + exp(-2u)), u = 0.79788456*(x + 0.044715 x^3)
// = x * rcp(1 + exp2(-2.30220826 * x * (1 + 0.044715 x^2)))   [rcp/exp2 err ~1e-7 << bf16]
__device__ __forceinline__ float gelu_fast(float x) {
  float arg = -2.30220826f * x * __builtin_fmaf(0.044715f, x * x, 1.0f);
  float e = __builtin_amdgcn_exp2f(arg);
  return x * __builtin_amdgcn_rcpf(1.0f + e);
}

// XCD-chunk swizzle (nwg % 8 == 0): logical sequence contiguous per XCD.
__device__ __forceinline__ int xcd_chunk(int bx, int nwg) {
  return (bx & 7) * (nwg >> 3) + (bx >> 3);
}

// ---------------- Prepack (+ block-0 group sort); biases NOT converted ----------------
__global__ __launch_bounds__(256) void prepack_sort_kernel(
    const float* __restrict__ w1t, const float* __restrict__ w2t,
    const float* __restrict__ x, const float* __restrict__ w1c,
    const float* __restrict__ w2c, short* __restrict__ wsb,
    const int* __restrict__ eidx, int* __restrict__ order, int* __restrict__ order2) {
  if (blockIdx.x == 0) {
    __shared__ int keys[NCHAIN];
    __shared__ int keys2[NBH];
    __shared__ int cnt[NGROUP + 1];
    __shared__ int cnt2[NGROUP + 1];
    const int t = threadIdx.x;
    for (int i = t; i <= NGROUP; i += 256) { cnt[i] = 0; cnt2[i] = 0; }
    __syncthreads();
    for (int i = t; i < NCHAIN; i += 256) {
      int h = (i >> 1) % NHEAD;
      int key = eidx[i] * NHEAD + h;
      keys[i] = key;
      atomicAdd(&cnt[key + 1], 1);
    }
    for (int i = t; i < NBH; i += 256) {
      int h = i % NHEAD;
      int key = eidx[i * TOPK] * NHEAD + h;
      keys2[i] = key;
      atomicAdd(&cnt2[key + 1], 1);
    }
    __syncthreads();
    if (t == 0) for (int i = 1; i <= NGROUP; ++i) cnt[i] += cnt[i - 1];
    if (t == 1) for (int i = 1; i <= NGROUP; ++i) cnt2[i] += cnt2[i - 1];
    __syncthreads();
    for (int i = t; i < NCHAIN; i += 256) {
      int pos = atomicAdd(&cnt[keys[i]], 1);  // rank within group (order-agnostic downstream)
      order[pos] = i;
    }
    for (int i = t; i < NBH; i += 256) {
      int pos = atomicAdd(&cnt2[keys2[i]], 1);
      order2[pos] = i;
    }
  }

  const size_t C1 = SZ_W1T / 8, C2 = C1 + SZ_W2T / 8, C3 = C2 + SZ_X / 8,
               C4 = C3 + SZ_W1C / 8, C5 = C4 + SZ_W2C / 8;
  for (size_t i = (size_t)blockIdx.x * blockDim.x + threadIdx.x; i < C5;
       i += (size_t)gridDim.x * blockDim.x) {
    const float* s; size_t doff;
    if (i < C1)      { s = w1t + i * 8;        doff = OFF_W1T + i * 8; }
    else if (i < C2) { s = w2t + (i - C1) * 8; doff = OFF_W2T + (i - C1) * 8; }
    else if (i < C3) { s = x   + (i - C2) * 8; doff = OFF_X   + (i - C2) * 8; }
    else if (i < C4) { s = w1c + (i - C3) * 8; doff = OFF_W1C + (i - C3) * 8; }
    else             { s = w2c + (i - C4) * 8; doff = OFF_W2C + (i - C4) * 8; }
    *(bf16x8*)(wsb + doff) = ld_gfrag(s);
  }
}

// ---------------- Kernel A v4 (e-half split: 32 e per pipeline stage) ----------------
// grid = 768*2. logical L (XCD-chunked): sid = L>>1 -> chain = order[sid], eblk = L&1.
// Wave w owns e in [eblk*256 + w*64, +64), processed as two 32-e halves with
// non-overlapping acc1/acc2 lifetimes (peak regs ~ halved vs R14 -> higher occupancy).
template <bool PP>
__global__ __launch_bounds__(256) void mixer_h_kernel(
    const float* __restrict__ x, const int* __restrict__ eidx,
    const float* __restrict__ w1t, const float* __restrict__ w1c, const float* __restrict__ b1,
    const short* __restrict__ wsb, const int* __restrict__ order, short* __restrict__ hws) {
  __shared__ __align__(16) char smem[SMA_TOTAL];
  const int L = xcd_chunk(blockIdx.x, NCHAIN * 2);
  const int sid = L >> 1, eblk = L & 1;
  const int bhk = PP ? order[sid] : sid;
  const int h = (bhk >> 1) % NHEAD;
  const int tid = threadIdx.x, w = tid >> 6, lane = tid & 63, lr = lane & 15, lg = lane >> 4;

  const int e = eidx[bhk];
  const size_t eh = (size_t)e * NHEAD + h;
  short* H = hws + (size_t)bhk * HDIM * HIDD;
  const float* B1f = b1 + eh * HDIM * HIDD;
  char* t1 = smem + w * T1_W;

  #pragma unroll 1
  for (int ehalf = 0; ehalf < 2; ++ehalf) {
    const int e0 = eblk * 256 + w * 64 + ehalf * 32;

    // MFMA1: T1[d][e] = sum_n X[d,n]*W1t[e,n];  D: col=e=lr, row=d=lg*4+i
    f32x4 acc1[2][4];  // [et][dt]
    #pragma unroll
    for (int et = 0; et < 2; ++et)
      #pragma unroll
      for (int dt = 0; dt < 4; ++dt) acc1[et][dt] = (f32x4){0.f, 0.f, 0.f, 0.f};
    #pragma unroll
    for (int ks = 0; ks < 8; ++ks) {
      bf16x8 wfr[2];
      #pragma unroll
      for (int et = 0; et < 2; ++et) {
        if (PP) wfr[et] = *(const bf16x8*)(wsb + OFF_W1T + eh * HIDD * NTOK +
                                           (size_t)(e0 + et * 16 + lr) * NTOK + ks * 32 + lg * 8);
        else    wfr[et] = ld_gfrag(w1t + eh * HIDD * NTOK +
                                   (size_t)(e0 + et * 16 + lr) * NTOK + ks * 32 + lg * 8);
      }
      #pragma unroll
      for (int dt = 0; dt < 4; ++dt) {
        bf16x8 xfr;
        if (PP) xfr = *(const bf16x8*)(wsb + OFF_X + (size_t)(bhk >> 1) * HDIM * NTOK +
                                       (size_t)(dt * 16 + lr) * NTOK + ks * 32 + lg * 8);
        else    xfr = ld_gfrag(x + (size_t)(bhk >> 1) * HDIM * NTOK +
                               (size_t)(dt * 16 + lr) * NTOK + ks * 32 + lg * 8);
        acc1[0][dt] = MFMA16(xfr, wfr[0], acc1[0][dt]);
        acc1[1][dt] = MFMA16(xfr, wfr[1], acc1[1][dt]);
      }
    }

    // relayout T1^T via wave-private LDS (col=e=lr, row=d=dt*16+lg*4+i) -> [e][d]
    #pragma unroll
    for (int et = 0; et < 2; ++et)
      #pragma unroll
      for (int dt = 0; dt < 4; ++dt) {
        bf16x4 p;
        #pragma unroll
        for (int i = 0; i < 4; ++i) p[i] = f2bf(acc1[et][dt][i]);
        *(bf16x4*)(t1 + (et * 16 + lr) * P_T1 + (dt * 16 + lg * 4) * 2) = p;
      }

    // MFMA2: T2^T[e][c] = sum_d T1^T[e,d]*W1c[c,d] + B1;  D: col=c=lr, row=e=lg*4+i
    f32x4 acc2[2][4];  // [et][ct]  (acc1 dead by here -> regs reused)
    #pragma unroll
    for (int et = 0; et < 2; ++et)
      #pragma unroll
      for (int ct = 0; ct < 4; ++ct)
        acc2[et][ct] = *(const f32x4*)(B1f + (size_t)(ct * 16 + lr) * HIDD + e0 + et * 16 + lg * 4);
    #pragma unroll
    for (int ks = 0; ks < 2; ++ks) {
      bf16x8 a[2];
      #pragma unroll
      for (int et = 0; et < 2; ++et)
        a[et] = *(const bf16x8*)(t1 + (et * 16 + lr) * P_T1 + (ks * 32 + lg * 8) * 2);
      #pragma unroll
      for (int ct = 0; ct < 4; ++ct) {
        bf16x8 bfr;
        if (PP) bfr = *(const bf16x8*)(wsb + OFF_W1C + eh * HDIM * HDIM +
                                       (size_t)(ct * 16 + lr) * HDIM + ks * 32 + lg * 8);
        else    bfr = ld_gfrag(w1c + eh * HDIM * HDIM +
                               (size_t)(ct * 16 + lr) * HDIM + ks * 32 + lg * 8);
        #pragma unroll
        for (int et = 0; et < 2; ++et) acc2[et][ct] = MFMA16(a[et], bfr, acc2[et][ct]);
      }
    }

    // GELU + store H[c][e] (col=c=lr, row=e=lg*4+i)
    #pragma unroll
    for (int et = 0; et < 2; ++et)
      #pragma unroll
      for (int ct = 0; ct < 4; ++ct) {
        bf16x4 g;
        #pragma unroll
        for (int i = 0; i < 4; ++i) g[i] = f2bf(gelu_fast(acc2[et][ct][i]));
        *(bf16x4*)(H + (size_t)(ct * 16 + lr) * HIDD + e0 + et * 16 + lg * 4) = g;
      }
  }
}

// ---------------- Kernel B v6 (64c x 64n per wave, intensity 2) ----------------
// grid = 768 x 256. L = xcd_chunk(bx, 768): sid = L>>1 -> bh = order2[sid], nhalf = L&1.
// Wave w: kk = w>>1, wq = w&1; n rows [nhalf*128 + wq*64, +64). k=1 waves publish
// weighted partials via LDS (aliases dead t3), k=0 waves combine + plain f32 stores.
template <bool PP>
__global__ __launch_bounds__(256) void mixer_out_kernel(
    const int* __restrict__ eidx, const float* __restrict__ ewt,
    const float* __restrict__ w2t, const float* __restrict__ w2c, const float* __restrict__ b2,
    const short* __restrict__ wsb, const int* __restrict__ order2,
    const short* __restrict__ hws, float* __restrict__ out) {
  __shared__ __align__(16) char smem[SMB_TOTAL];
  const int L = xcd_chunk(blockIdx.x, NBH * 2);
  const int sid = L >> 1, nhalf = L & 1;
  const int bh = PP ? order2[sid] : sid;
  const int h = bh % NHEAD;
  const int tid = threadIdx.x, w = tid >> 6, lane = tid & 63, lr = lane & 15, lg = lane >> 4;
  const int kk = w >> 1, wq = w & 1;
  const int nb = nhalf * 128 + wq * 64;
  char* t3 = smem + w * T3_W;
  float* OUT = out + (size_t)bh * HDIM * NTOK;

  const int e = eidx[bh * TOPK + kk];
  const float wk = ewt[bh * TOPK + kk];
  const size_t eh = (size_t)e * NHEAD + h;
  const short* Hk = hws + (size_t)(bh * TOPK + kk) * HDIM * HIDD;
  const float* B2f = b2 + eh * HDIM * NTOK;

  // MFMA3: T3[c][n] = sum_e H[c,e]*W2t[n,e];  A=H (m=c), B=W2t (n=n), k=e
  f32x4 acc3[4][4];  // [ct][nt]
  #pragma unroll
  for (int ct = 0; ct < 4; ++ct)
    #pragma unroll
    for (int nt = 0; nt < 4; ++nt) acc3[ct][nt] = (f32x4){0.f, 0.f, 0.f, 0.f};
  #pragma unroll 4
  for (int ks = 0; ks < 16; ++ks) {
    bf16x8 a[4];
    #pragma unroll
    for (int ct = 0; ct < 4; ++ct)
      a[ct] = *(const bf16x8*)(Hk + (size_t)(ct * 16 + lr) * HIDD + ks * 32 + lg * 8);
    #pragma unroll
    for (int nt = 0; nt < 4; ++nt) {
      bf16x8 bfr;
      if (PP) bfr = *(const bf16x8*)(wsb + OFF_W2T + eh * NTOK * HIDD +
                                     (size_t)(nb + nt * 16 + lr) * HIDD + ks * 32 + lg * 8);
      else    bfr = ld_gfrag(w2t + eh * NTOK * HIDD +
                             (size_t)(nb + nt * 16 + lr) * HIDD + ks * 32 + lg * 8);
      #pragma unroll
      for (int ct = 0; ct < 4; ++ct) acc3[ct][nt] = MFMA16(a[ct], bfr, acc3[ct][nt]);
    }
  }

  // relayout T3^T via wave-private LDS (col=n=lr, row=c=ct*16+lg*4+i) -> [n][c]
  #pragma unroll
  for (int ct = 0; ct < 4; ++ct)
    #pragma unroll
    for (int nt = 0; nt < 4; ++nt) {
      bf16x4 p;
      #pragma unroll
      for (int i = 0; i < 4; ++i) p[i] = f2bf(acc3[ct][nt][i]);
      *(bf16x4*)(t3 + (nt * 16 + lr) * P_T3 + (ct * 16 + lg * 4) * 2) = p;
    }

  // MFMA4: OUT^T[n][co] = sum_c T3^T[n,c]*W2c[co,c]
  f32x4 acc4[4][4];  // [nt][cot]
  #pragma unroll
  for (int nt = 0; nt < 4; ++nt)
    #pragma unroll
    for (int ct = 0; ct < 4; ++ct) acc4[nt][ct] = (f32x4){0.f, 0.f, 0.f, 0.f};
  #pragma unroll
  for (int ks = 0; ks < 2; ++ks) {
    bf16x8 a[4];
    #pragma unroll
    for (int nt = 0; nt < 4; ++nt)
      a[nt] = *(const bf16x8*)(t3 + (nt * 16 + lr) * P_T3 + (ks * 32 + lg * 8) * 2);
    #pragma unroll
    for (int ct = 0; ct < 4; ++ct) {
      bf16x8 bfr;
      if (PP) bfr = *(const bf16x8*)(wsb + OFF_W2C + eh * HDIM * HDIM +
                                     (size_t)(ct * 16 + lr) * HDIM + ks * 32 + lg * 8);
      else    bfr = ld_gfrag(w2c + eh * HDIM * HDIM +
                             (size_t)(ct * 16 + lr) * HDIM + ks * 32 + lg * 8);
      #pragma unroll
      for (int nt = 0; nt < 4; ++nt) acc4[nt][ct] = MFMA16(a[nt], bfr, acc4[nt][ct]);
    }
  }

  // weighted partial in place: acc4 = wk*(acc4 + B2)  (col=co=lr, row=n=lg*4+i)
  #pragma unroll
  for (int nt = 0; nt < 4; ++nt)
    #pragma unroll
    for (int cot = 0; cot < 4; ++cot) {
      const int co = cot * 16 + lr;
      const int n0 = nb + nt * 16 + lg * 4;
      f32x4 bb = *(const f32x4*)(B2f + (size_t)co * NTOK + n0);
      #pragma unroll
      for (int i = 0; i < 4; ++i) acc4[nt][cot][i] = wk * (acc4[nt][cot][i] + bb[i]);
    }

  __syncthreads();  // all waves done reading their t3 (comb aliases t3 region)

  // k=1 waves publish partials: comb[wq] = [64 n][64 co] f32 at offset wq*16384
  if (kk == 1) {
    float* comb = (float*)(smem + wq * 16384);
    #pragma unroll
    for (int nt = 0; nt < 4; ++nt)
      #pragma unroll
      for (int cot = 0; cot < 4; ++cot) {
        const int co = cot * 16 + lr;
        #pragma unroll
        for (int i = 0; i < 4; ++i)
          comb[(nt * 16 + lg * 4 + i) * 64 + co] = acc4[nt][cot][i];
      }
  }
  __syncthreads();

  // k=0 waves combine + store (each (co,n) written exactly once across the grid)
  if (kk == 0) {
    const float* comb = (const float*)(smem + wq * 16384);
    #pragma unroll
    for (int nt = 0; nt < 4; ++nt)
      #pragma unroll
      for (int cot = 0; cot < 4; ++cot) {
        const int co = cot * 16 + lr;
        const int n0 = nb + nt * 16 + lg * 4;
        f32x4 v;
        #pragma unroll
        for (int i = 0; i < 4; ++i)
          v[i] = acc4[nt][cot][i] + comb[(nt * 16 + lg * 4 + i) * 64 + co];
        *(f32x4*)(OUT + (size_t)co * NTOK + n0) = v;
      }
  }
}

extern "C" void kernel_launch(void* const* d_in, const int* in_sizes, int n_in,
                              void* d_out, int out_size, void* d_ws, size_t ws_size,
                              hipStream_t stream) {
  const float* x   = (const float*)d_in[0];
  const int*   ei  = (const int*)d_in[1];
  const float* ew  = (const float*)d_in[2];
  const float* w1t = (const float*)d_in[3];
  const float* w1c = (const float*)d_in[4];
  const float* b1  = (const float*)d_in[5];
  const float* w2t = (const float*)d_in[6];
  const float* w2c = (const float*)d_in[7];
  const float* b2  = (const float*)d_in[8];
  float* out = (float*)d_out;
  short* wsb = (short*)d_ws;
  short* hws = wsb + OFF_H;
  int* order  = (int*)(wsb + TOTEL);
  int* order2 = order + NCHAIN;

  if (ws_size >= NEED) {
    prepack_sort_kernel<<<dim3(2048), dim3(256), 0, stream>>>(
        w1t, w2t, x, w1c, w2c, wsb, ei, order, order2);
    mixer_h_kernel<true><<<dim3(NCHAIN * 2), dim3(256), 0, stream>>>(
        x, ei, w1t, w1c, b1, wsb, order, hws);
    mixer_out_kernel<true><<<dim3(NBH * 2), dim3(256), 0, stream>>>(
        ei, ew, w2t, w2c, b2, wsb, order2, hws, out);
  } else {
    mixer_h_kernel<false><<<dim3(NCHAIN * 2), dim3(256), 0, stream>>>(
        x, ei, w1t, w1c, b1, wsb, order, hws);
    mixer_out_kernel<false><<<dim3(NBH * 2), dim3(256), 0, stream>>>(
        ei, ew, w2t, w2c, b2, wsb, order2, hws, out);
  }
}

// Round 16
// 165.669 us; speedup vs baseline: 1.0871x; 1.0871x over previous
//
#include <hip/hip_runtime.h>
#include <hip/hip_bf16.h>

// MultiHeadBatchedMixers, group-sorted two-kernel structure (no atomics):
//   prepack+sort: w1t,w2t,x,w1c,w2c -> bf16 ws (biases stay f32; L2-hot);
//                 block 0 builds order[768] (by (e,h)) / order2[384] (by (e0,h))
//   Kernel A (grid 1536x256, XCD-chunked, group-ordered): H = GELU(W1c @ X @ W1t^T + B1)
//       wave owns 64 e, single pass (R14 structure; R15's e-half split REVERTED)
//   Kernel B (grid 768x256, XCD-chunked, group-ordered): 4 waves = 2 k x 2 wq,
//       wave owns 64c x 64n (intensity 2); LDS combine; plain f32 stores
// bf16 MFMA 16x16x32, f32 accumulate.
// NOTE (R8/R10): VGPR+AGPR share one file on gfx950; never min-waves-bound the
// MFMA kernels (reg cap -> accumulator spill -> WRITE blowup).
// NOTE (R12/R13/R14): cost tracks TOTAL load instructions & MFMA/load intensity;
// intensity-2 64x64 wave tiles beat high-occupancy thin tiles.
// NOTE (R15): e-half splitting a wave tile SERIALIZES phases (LDS/reg reuse dep),
// halves ILP, and does NOT reduce peak registers — occupancy fell 19.7->10.3%.

namespace {
constexpr int NHEAD = 12, NTOK = 256, HDIM = 64, HIDD = 512, NBATCH = 32, TOPK = 2;
constexpr int NCHAIN = NBATCH * NHEAD * TOPK;  // 768
constexpr int NBH = NBATCH * NHEAD;            // 384
constexpr int NGROUP = 8 * NHEAD;              // 96

// Kernel A LDS: per-wave T1^T [64 e][64 d] bf16, pitch +16B
constexpr int P_T1 = HDIM * 2 + 16;   // 144
constexpr int T1_W = 64 * P_T1;       // 9216
constexpr int SMA_TOTAL = 4 * T1_W;   // 36864
// Kernel B LDS: per-wave T3^T [64 n][64 c] (4 waves); combine aliases [0,32768)
constexpr int P_T3 = HDIM * 2 + 16;   // 144
constexpr int T3_W = 64 * P_T3;       // 9216
constexpr int SMB_TOTAL = 4 * T3_W;   // 36864

// ws layout: [H][w1t][w2t][x][b1(unused)][b2(unused)][w1c][w2c] bf16, then orders
constexpr size_t SZ_H    = (size_t)NCHAIN * HDIM * HIDD;          // 25,165,824
constexpr size_t OFF_H   = 0;
constexpr size_t OFF_W1T = OFF_H + SZ_H;
constexpr size_t SZ_W1T  = (size_t)8 * NHEAD * HIDD * NTOK;       // 12,582,912
constexpr size_t OFF_W2T = OFF_W1T + SZ_W1T;
constexpr size_t SZ_W2T  = (size_t)8 * NHEAD * NTOK * HIDD;
constexpr size_t OFF_X   = OFF_W2T + SZ_W2T;
constexpr size_t SZ_X    = (size_t)NBATCH * NHEAD * HDIM * NTOK;  // 6,291,456
constexpr size_t OFF_B1  = OFF_X + SZ_X;
constexpr size_t SZ_B1   = (size_t)8 * NHEAD * HDIM * HIDD;
constexpr size_t OFF_B2  = OFF_B1 + SZ_B1;
constexpr size_t SZ_B2   = (size_t)8 * NHEAD * HDIM * NTOK;
constexpr size_t OFF_W1C = OFF_B2 + SZ_B2;
constexpr size_t SZ_W1C  = (size_t)8 * NHEAD * HDIM * HDIM;       // 393,216
constexpr size_t OFF_W2C = OFF_W1C + SZ_W1C;
constexpr size_t SZ_W2C  = (size_t)8 * NHEAD * HDIM * HDIM;
constexpr size_t TOTEL   = OFF_W2C + SZ_W2C;                      // shorts
constexpr size_t NEED    = TOTEL * 2 + (NCHAIN + NBH) * 4;
}

typedef float f32x4 __attribute__((ext_vector_type(4)));
typedef short bf16x8 __attribute__((ext_vector_type(8)));
typedef short bf16x4 __attribute__((ext_vector_type(4)));

#define MFMA16(a, b, c) __builtin_amdgcn_mfma_f32_16x16x32_bf16((a), (b), (c), 0, 0, 0)

__device__ __forceinline__ short f2bf(float f) {
  union { float f; unsigned u; } v; v.f = f;
  unsigned r = v.u + 0x7fffu + ((v.u >> 16) & 1u);
  return (short)(r >> 16);
}

__device__ __forceinline__ bf16x8 ld_gfrag(const float* p) {
  float4 a = *(const float4*)p;
  float4 b = *(const float4*)(p + 4);
  bf16x8 r;
  r[0] = f2bf(a.x); r[1] = f2bf(a.y); r[2] = f2bf(a.z); r[3] = f2bf(a.w);
  r[4] = f2bf(b.x); r[5] = f2bf(b.y); r[6] = f2bf(b.z); r[7] = f2bf(b.w);
  return r;
}

// gelu(x) = x * rcp(1 + exp2(-2.30220826 * x * (1 + 0.044715 x^2)))  [err ~1e-7 << bf16]
__device__ __forceinline__ float gelu_fast(float x) {
  float arg = -2.30220826f * x * __builtin_fmaf(0.044715f, x * x, 1.0f);
  float e = __builtin_amdgcn_exp2f(arg);
  return x * __builtin_amdgcn_rcpf(1.0f + e);
}

// XCD-chunk swizzle (nwg % 8 == 0): logical sequence contiguous per XCD.
__device__ __forceinline__ int xcd_chunk(int bx, int nwg) {
  return (bx & 7) * (nwg >> 3) + (bx >> 3);
}

// ---------------- Prepack (+ block-0 group sort); biases NOT converted ----------------
__global__ __launch_bounds__(256) void prepack_sort_kernel(
    const float* __restrict__ w1t, const float* __restrict__ w2t,
    const float* __restrict__ x, const float* __restrict__ w1c,
    const float* __restrict__ w2c, short* __restrict__ wsb,
    const int* __restrict__ eidx, int* __restrict__ order, int* __restrict__ order2) {
  if (blockIdx.x == 0) {
    __shared__ int keys[NCHAIN];
    __shared__ int keys2[NBH];
    __shared__ int cnt[NGROUP + 1];
    __shared__ int cnt2[NGROUP + 1];
    const int t = threadIdx.x;
    for (int i = t; i <= NGROUP; i += 256) { cnt[i] = 0; cnt2[i] = 0; }
    __syncthreads();
    for (int i = t; i < NCHAIN; i += 256) {
      int h = (i >> 1) % NHEAD;
      int key = eidx[i] * NHEAD + h;
      keys[i] = key;
      atomicAdd(&cnt[key + 1], 1);
    }
    for (int i = t; i < NBH; i += 256) {
      int h = i % NHEAD;
      int key = eidx[i * TOPK] * NHEAD + h;
      keys2[i] = key;
      atomicAdd(&cnt2[key + 1], 1);
    }
    __syncthreads();
    if (t == 0) for (int i = 1; i <= NGROUP; ++i) cnt[i] += cnt[i - 1];
    if (t == 1) for (int i = 1; i <= NGROUP; ++i) cnt2[i] += cnt2[i - 1];
    __syncthreads();
    for (int i = t; i < NCHAIN; i += 256) {
      int pos = atomicAdd(&cnt[keys[i]], 1);  // rank within group (order-agnostic downstream)
      order[pos] = i;
    }
    for (int i = t; i < NBH; i += 256) {
      int pos = atomicAdd(&cnt2[keys2[i]], 1);
      order2[pos] = i;
    }
  }

  const size_t C1 = SZ_W1T / 8, C2 = C1 + SZ_W2T / 8, C3 = C2 + SZ_X / 8,
               C4 = C3 + SZ_W1C / 8, C5 = C4 + SZ_W2C / 8;
  for (size_t i = (size_t)blockIdx.x * blockDim.x + threadIdx.x; i < C5;
       i += (size_t)gridDim.x * blockDim.x) {
    const float* s; size_t doff;
    if (i < C1)      { s = w1t + i * 8;        doff = OFF_W1T + i * 8; }
    else if (i < C2) { s = w2t + (i - C1) * 8; doff = OFF_W2T + (i - C1) * 8; }
    else if (i < C3) { s = x   + (i - C2) * 8; doff = OFF_X   + (i - C2) * 8; }
    else if (i < C4) { s = w1c + (i - C3) * 8; doff = OFF_W1C + (i - C3) * 8; }
    else             { s = w2c + (i - C4) * 8; doff = OFF_W2C + (i - C4) * 8; }
    *(bf16x8*)(wsb + doff) = ld_gfrag(s);
  }
}

// ---------------- Kernel A (64 e per wave, R14 structure) ----------------
// grid = 768*2. logical L (XCD-chunked): sid = L>>1 -> chain = order[sid], eblk = L&1.
template <bool PP>
__global__ __launch_bounds__(256) void mixer_h_kernel(
    const float* __restrict__ x, const int* __restrict__ eidx,
    const float* __restrict__ w1t, const float* __restrict__ w1c, const float* __restrict__ b1,
    const short* __restrict__ wsb, const int* __restrict__ order, short* __restrict__ hws) {
  __shared__ __align__(16) char smem[SMA_TOTAL];
  const int L = xcd_chunk(blockIdx.x, NCHAIN * 2);
  const int sid = L >> 1, eblk = L & 1;
  const int bhk = PP ? order[sid] : sid;
  const int h = (bhk >> 1) % NHEAD;
  const int tid = threadIdx.x, w = tid >> 6, lane = tid & 63, lr = lane & 15, lg = lane >> 4;

  const int e = eidx[bhk];
  const size_t eh = (size_t)e * NHEAD + h;
  short* H = hws + (size_t)bhk * HDIM * HIDD;
  const float* B1f = b1 + eh * HDIM * HIDD;

  const int e0 = eblk * 256 + w * 64;

  // MFMA1: T1[d][e] = sum_n X[d,n]*W1t[e,n];  A=X (m=d), B=W1t (n=e), k=n
  f32x4 acc1[4][4];  // [et][dt]
  #pragma unroll
  for (int et = 0; et < 4; ++et)
    #pragma unroll
    for (int dt = 0; dt < 4; ++dt) acc1[et][dt] = (f32x4){0.f, 0.f, 0.f, 0.f};
  #pragma unroll
  for (int ks = 0; ks < 8; ++ks) {
    bf16x8 wfr[4];
    #pragma unroll
    for (int et = 0; et < 4; ++et) {
      if (PP) wfr[et] = *(const bf16x8*)(wsb + OFF_W1T + eh * HIDD * NTOK +
                                         (size_t)(e0 + et * 16 + lr) * NTOK + ks * 32 + lg * 8);
      else    wfr[et] = ld_gfrag(w1t + eh * HIDD * NTOK +
                                 (size_t)(e0 + et * 16 + lr) * NTOK + ks * 32 + lg * 8);
    }
    #pragma unroll
    for (int dt = 0; dt < 4; ++dt) {
      bf16x8 xfr;
      if (PP) xfr = *(const bf16x8*)(wsb + OFF_X + (size_t)(bhk >> 1) * HDIM * NTOK +
                                     (size_t)(dt * 16 + lr) * NTOK + ks * 32 + lg * 8);
      else    xfr = ld_gfrag(x + (size_t)(bhk >> 1) * HDIM * NTOK +
                             (size_t)(dt * 16 + lr) * NTOK + ks * 32 + lg * 8);
      #pragma unroll
      for (int et = 0; et < 4; ++et) acc1[et][dt] = MFMA16(xfr, wfr[et], acc1[et][dt]);
    }
  }

  // relayout T1^T via wave-private LDS (col=e=lr, row=d=dt*16+lg*4+i) -> [e][d]
  char* t1 = smem + w * T1_W;
  #pragma unroll
  for (int et = 0; et < 4; ++et)
    #pragma unroll
    for (int dt = 0; dt < 4; ++dt) {
      bf16x4 p;
      #pragma unroll
      for (int i = 0; i < 4; ++i) p[i] = f2bf(acc1[et][dt][i]);
      *(bf16x4*)(t1 + (et * 16 + lr) * P_T1 + (dt * 16 + lg * 4) * 2) = p;
    }

  // MFMA2: T2^T[e][c] = sum_d T1^T[e,d]*W1c[c,d] + B1;  D: col=c=lr, row=e=lg*4+i
  f32x4 acc2[4][4];  // [et][ct]
  #pragma unroll
  for (int et = 0; et < 4; ++et)
    #pragma unroll
    for (int ct = 0; ct < 4; ++ct)
      acc2[et][ct] = *(const f32x4*)(B1f + (size_t)(ct * 16 + lr) * HIDD + e0 + et * 16 + lg * 4);
  #pragma unroll
  for (int ks = 0; ks < 2; ++ks) {
    bf16x8 a[4];
    #pragma unroll
    for (int et = 0; et < 4; ++et)
      a[et] = *(const bf16x8*)(t1 + (et * 16 + lr) * P_T1 + (ks * 32 + lg * 8) * 2);
    #pragma unroll
    for (int ct = 0; ct < 4; ++ct) {
      bf16x8 bfr;
      if (PP) bfr = *(const bf16x8*)(wsb + OFF_W1C + eh * HDIM * HDIM +
                                     (size_t)(ct * 16 + lr) * HDIM + ks * 32 + lg * 8);
      else    bfr = ld_gfrag(w1c + eh * HDIM * HDIM +
                             (size_t)(ct * 16 + lr) * HDIM + ks * 32 + lg * 8);
      #pragma unroll
      for (int et = 0; et < 4; ++et) acc2[et][ct] = MFMA16(a[et], bfr, acc2[et][ct]);
    }
  }

  // GELU + store H[c][e] (col=c=lr, row=e=lg*4+i)
  #pragma unroll
  for (int et = 0; et < 4; ++et)
    #pragma unroll
    for (int ct = 0; ct < 4; ++ct) {
      bf16x4 g;
      #pragma unroll
      for (int i = 0; i < 4; ++i) g[i] = f2bf(gelu_fast(acc2[et][ct][i]));
      *(bf16x4*)(H + (size_t)(ct * 16 + lr) * HIDD + e0 + et * 16 + lg * 4) = g;
    }
}

// ---------------- Kernel B v6 (64c x 64n per wave, intensity 2) ----------------
// grid = 768 x 256. L = xcd_chunk(bx, 768): sid = L>>1 -> bh = order2[sid], nhalf = L&1.
// Wave w: kk = w>>1, wq = w&1; n rows [nhalf*128 + wq*64, +64). k=1 waves publish
// weighted partials via LDS (aliases dead t3), k=0 waves combine + plain f32 stores.
template <bool PP>
__global__ __launch_bounds__(256) void mixer_out_kernel(
    const int* __restrict__ eidx, const float* __restrict__ ewt,
    const float* __restrict__ w2t, const float* __restrict__ w2c, const float* __restrict__ b2,
    const short* __restrict__ wsb, const int* __restrict__ order2,
    const short* __restrict__ hws, float* __restrict__ out) {
  __shared__ __align__(16) char smem[SMB_TOTAL];
  const int L = xcd_chunk(blockIdx.x, NBH * 2);
  const int sid = L >> 1, nhalf = L & 1;
  const int bh = PP ? order2[sid] : sid;
  const int h = bh % NHEAD;
  const int tid = threadIdx.x, w = tid >> 6, lane = tid & 63, lr = lane & 15, lg = lane >> 4;
  const int kk = w >> 1, wq = w & 1;
  const int nb = nhalf * 128 + wq * 64;
  char* t3 = smem + w * T3_W;
  float* OUT = out + (size_t)bh * HDIM * NTOK;

  const int e = eidx[bh * TOPK + kk];
  const float wk = ewt[bh * TOPK + kk];
  const size_t eh = (size_t)e * NHEAD + h;
  const short* Hk = hws + (size_t)(bh * TOPK + kk) * HDIM * HIDD;
  const float* B2f = b2 + eh * HDIM * NTOK;

  // MFMA3: T3[c][n] = sum_e H[c,e]*W2t[n,e];  A=H (m=c), B=W2t (n=n), k=e
  f32x4 acc3[4][4];  // [ct][nt]
  #pragma unroll
  for (int ct = 0; ct < 4; ++ct)
    #pragma unroll
    for (int nt = 0; nt < 4; ++nt) acc3[ct][nt] = (f32x4){0.f, 0.f, 0.f, 0.f};
  #pragma unroll 4
  for (int ks = 0; ks < 16; ++ks) {
    bf16x8 a[4];
    #pragma unroll
    for (int ct = 0; ct < 4; ++ct)
      a[ct] = *(const bf16x8*)(Hk + (size_t)(ct * 16 + lr) * HIDD + ks * 32 + lg * 8);
    #pragma unroll
    for (int nt = 0; nt < 4; ++nt) {
      bf16x8 bfr;
      if (PP) bfr = *(const bf16x8*)(wsb + OFF_W2T + eh * NTOK * HIDD +
                                     (size_t)(nb + nt * 16 + lr) * HIDD + ks * 32 + lg * 8);
      else    bfr = ld_gfrag(w2t + eh * NTOK * HIDD +
                             (size_t)(nb + nt * 16 + lr) * HIDD + ks * 32 + lg * 8);
      #pragma unroll
      for (int ct = 0; ct < 4; ++ct) acc3[ct][nt] = MFMA16(a[ct], bfr, acc3[ct][nt]);
    }
  }

  // relayout T3^T via wave-private LDS (col=n=lr, row=c=ct*16+lg*4+i) -> [n][c]
  #pragma unroll
  for (int ct = 0; ct < 4; ++ct)
    #pragma unroll
    for (int nt = 0; nt < 4; ++nt) {
      bf16x4 p;
      #pragma unroll
      for (int i = 0; i < 4; ++i) p[i] = f2bf(acc3[ct][nt][i]);
      *(bf16x4*)(t3 + (nt * 16 + lr) * P_T3 + (ct * 16 + lg * 4) * 2) = p;
    }

  // MFMA4: OUT^T[n][co] = sum_c T3^T[n,c]*W2c[co,c]
  f32x4 acc4[4][4];  // [nt][cot]
  #pragma unroll
  for (int nt = 0; nt < 4; ++nt)
    #pragma unroll
    for (int ct = 0; ct < 4; ++ct) acc4[nt][ct] = (f32x4){0.f, 0.f, 0.f, 0.f};
  #pragma unroll
  for (int ks = 0; ks < 2; ++ks) {
    bf16x8 a[4];
    #pragma unroll
    for (int nt = 0; nt < 4; ++nt)
      a[nt] = *(const bf16x8*)(t3 + (nt * 16 + lr) * P_T3 + (ks * 32 + lg * 8) * 2);
    #pragma unroll
    for (int ct = 0; ct < 4; ++ct) {
      bf16x8 bfr;
      if (PP) bfr = *(const bf16x8*)(wsb + OFF_W2C + eh * HDIM * HDIM +
                                     (size_t)(ct * 16 + lr) * HDIM + ks * 32 + lg * 8);
      else    bfr = ld_gfrag(w2c + eh * HDIM * HDIM +
                             (size_t)(ct * 16 + lr) * HDIM + ks * 32 + lg * 8);
      #pragma unroll
      for (int nt = 0; nt < 4; ++nt) acc4[nt][ct] = MFMA16(a[nt], bfr, acc4[nt][ct]);
    }
  }

  // weighted partial in place: acc4 = wk*(acc4 + B2)  (col=co=lr, row=n=lg*4+i)
  #pragma unroll
  for (int nt = 0; nt < 4; ++nt)
    #pragma unroll
    for (int cot = 0; cot < 4; ++cot) {
      const int co = cot * 16 + lr;
      const int n0 = nb + nt * 16 + lg * 4;
      f32x4 bb = *(const f32x4*)(B2f + (size_t)co * NTOK + n0);
      #pragma unroll
      for (int i = 0; i < 4; ++i) acc4[nt][cot][i] = wk * (acc4[nt][cot][i] + bb[i]);
    }

  __syncthreads();  // all waves done reading their t3 (comb aliases t3 region)

  // k=1 waves publish partials: comb[wq] = [64 n][64 co] f32 at offset wq*16384
  if (kk == 1) {
    float* comb = (float*)(smem + wq * 16384);
    #pragma unroll
    for (int nt = 0; nt < 4; ++nt)
      #pragma unroll
      for (int cot = 0; cot < 4; ++cot) {
        const int co = cot * 16 + lr;
        #pragma unroll
        for (int i = 0; i < 4; ++i)
          comb[(nt * 16 + lg * 4 + i) * 64 + co] = acc4[nt][cot][i];
      }
  }
  __syncthreads();

  // k=0 waves combine + store (each (co,n) written exactly once across the grid)
  if (kk == 0) {
    const float* comb = (const float*)(smem + wq * 16384);
    #pragma unroll
    for (int nt = 0; nt < 4; ++nt)
      #pragma unroll
      for (int cot = 0; cot < 4; ++cot) {
        const int co = cot * 16 + lr;
        const int n0 = nb + nt * 16 + lg * 4;
        f32x4 v;
        #pragma unroll
        for (int i = 0; i < 4; ++i)
          v[i] = acc4[nt][cot][i] + comb[(nt * 16 + lg * 4 + i) * 64 + co];
        *(f32x4*)(OUT + (size_t)co * NTOK + n0) = v;
      }
  }
}

extern "C" void kernel_launch(void* const* d_in, const int* in_sizes, int n_in,
                              void* d_out, int out_size, void* d_ws, size_t ws_size,
                              hipStream_t stream) {
  const float* x   = (const float*)d_in[0];
  const int*   ei  = (const int*)d_in[1];
  const float* ew  = (const float*)d_in[2];
  const float* w1t = (const float*)d_in[3];
  const float* w1c = (const float*)d_in[4];
  const float* b1  = (const float*)d_in[5];
  const float* w2t = (const float*)d_in[6];
  const float* w2c = (const float*)d_in[7];
  const float* b2  = (const float*)d_in[8];
  float* out = (float*)d_out;
  short* wsb = (short*)d_ws;
  short* hws = wsb + OFF_H;
  int* order  = (int*)(wsb + TOTEL);
  int* order2 = order + NCHAIN;

  if (ws_size >= NEED) {
    prepack_sort_kernel<<<dim3(2048), dim3(256), 0, stream>>>(
        w1t, w2t, x, w1c, w2c, wsb, ei, order, order2);
    mixer_h_kernel<true><<<dim3(NCHAIN * 2), dim3(256), 0, stream>>>(
        x, ei, w1t, w1c, b1, wsb, order, hws);
    mixer_out_kernel<true><<<dim3(NBH * 2), dim3(256), 0, stream>>>(
        ei, ew, w2t, w2c, b2, wsb, order2, hws, out);
  } else {
    mixer_h_kernel<false><<<dim3(NCHAIN * 2), dim3(256), 0, stream>>>(
        x, ei, w1t, w1c, b1, wsb, order, hws);
    mixer_out_kernel<false><<<dim3(NBH * 2), dim3(256), 0, stream>>>(
        ei, ew, w2t, w2c, b2, wsb, order2, hws, out);
  }
}